// Round 5
// baseline (2423.251 us; speedup 1.0000x reference)
//
#include <hip/hip_runtime.h>
#include <hip/hip_bf16.h>
#include <stdint.h>

#define BB 4
#define NN 16384
#define SS 1024
#define KSAMP 64
#define DD 256
#define CIN 259
#define HH 512
#define R2C 0.04f

// workspace offsets (bytes, all 256-aligned)
#define OFF_PTS  0ull            // bf16 pointsT [B][N][256]  33,554,432
#define OFF_Q    33554432ull     // f32 point norms [B][N]       262,144
#define OFF_W1P  33816576ull     // bf16 packed w1               294,912
#define OFF_W2P  34111488ull     // bf16 packed w2               524,288
#define OFF_CX   34635776ull     // f32 centers x [4096]
#define OFF_CY   34652160ull
#define OFF_CZ   34668544ull
#define OFF_BIDX 34684928ull     // int group idx [4096][64]   1,048,576

typedef __attribute__((ext_vector_type(8))) short bf16x8;
typedef __attribute__((ext_vector_type(4))) short bf16x4;
typedef __attribute__((ext_vector_type(4))) float f32x4;
typedef __attribute__((ext_vector_type(2))) float f32x2;

__device__ __forceinline__ unsigned short f2bf(float f) {
    unsigned u = __float_as_uint(f);
    u = u + 0x7fffu + ((u >> 16) & 1u);   // round-to-nearest-even
    return (unsigned short)(u >> 16);
}

// opaque identity: forbids rematerialization of the value (pins it live)
__device__ __forceinline__ void pin(f32x2& v) {
    asm volatile("" : "+v"(v));
}

// ---------------------------------------------------------------------------
// Kernel 1: fused FPS (blocks 0..3) + points transpose->bf16 (4..1027)
//           + point norms (1028..1091) + weight packing (1092,1093)
// amdgpu_waves_per_eu(4,4): 128-VGPR budget so FPS state stays in registers.
// ---------------------------------------------------------------------------
__global__ __launch_bounds__(1024)
__attribute__((amdgpu_waves_per_eu(4, 4)))
void k_prep(const float* __restrict__ xyz,
            const float* __restrict__ pts,
            const float* __restrict__ w1,
            const float* __restrict__ w2,
            unsigned char* __restrict__ ws)
{
    __shared__ __align__(16) unsigned char smem[64 * 264 * 2];
    const int blk = blockIdx.x;
    const int t   = threadIdx.x;

    if (blk < 4) {
        // ---------------- FPS, batch b = blk -------------------------------
        // 1024 threads, 16 points/thread (8 f32x2 pairs). One barrier/iter.
        // contract(off): keep mul/add as separate IEEE ops (match reference).
#pragma clang fp contract(off)
        const int b = blk;
        const float* xb = xyz + (size_t)b * 3 * NN;
        f32x2 x[8], y[8], z[8], d[8];
        const int base = t * 16;
        const float4* xv = (const float4*)(xb + base);
        const float4* yv = (const float4*)(xb + NN + base);
        const float4* zv = (const float4*)(xb + 2 * NN + base);
#pragma unroll
        for (int i = 0; i < 4; i++) {
            float4 a = xv[i]; x[2*i] = (f32x2){a.x, a.y}; x[2*i+1] = (f32x2){a.z, a.w};
            float4 c = yv[i]; y[2*i] = (f32x2){c.x, c.y}; y[2*i+1] = (f32x2){c.z, c.w};
            float4 e = zv[i]; z[2*i] = (f32x2){e.x, e.y}; z[2*i+1] = (f32x2){e.z, e.w};
        }
        // pin all point coords in registers: the asm output is opaque, so the
        // compiler cannot rematerialize these as per-iteration global re-loads
#pragma unroll
        for (int i = 0; i < 8; i++) { pin(x[i]); pin(y[i]); pin(z[i]); }
#pragma unroll
        for (int i = 0; i < 8; i++) d[i] = (f32x2){1e10f, 1e10f};

        unsigned long long* sK = (unsigned long long*)smem;  // [2][16] parity
        float* cxs = (float*)(ws + OFF_CX);
        float* cys = (float*)(ws + OFF_CY);
        float* czs = (float*)(ws + OFF_CZ);

        const int wv = t >> 6, lane = t & 63;
        // initial farthest = b (uniform broadcast load)
        float cx = xb[b], cy = xb[NN + b], cz = xb[2 * NN + b];

        for (int it = 0; it < SS; ++it) {
            if (t == 0) {
                cxs[(b << 10) + it] = cx;
                cys[(b << 10) + it] = cy;
                czs[(b << 10) + it] = cz;
            }
            if (it == SS - 1) break;

            const f32x2 cxp = (f32x2){cx, cx};
            const f32x2 cyp = (f32x2){cy, cy};
            const f32x2 czp = (f32x2){cz, cz};
            float bl = -1.0f;
            int   bi = 0;
#pragma unroll
            for (int k = 0; k < 8; k++) {
                f32x2 dx = x[k] - cxp;
                f32x2 dy = y[k] - cyp;
                f32x2 dz = z[k] - czp;
                f32x2 s  = dx * dx + dy * dy + dz * dz;  // no contraction
                float n0 = fminf(d[k].x, s.x);
                float n1 = fminf(d[k].y, s.y);
                d[k].x = n0;
                d[k].y = n1;
                if (n0 > bl) { bl = n0; bi = base + 2 * k; }
                if (n1 > bl) { bl = n1; bi = base + 2 * k + 1; }
            }
            // packed key: high = dist bits (nonneg -> monotone), low = ~idx
            unsigned long long key =
                ((unsigned long long)__float_as_uint(bl) << 32) |
                (unsigned)(0xFFFFFFFFu - (unsigned)bi);
            // wave reduce (max)
#pragma unroll
            for (int off = 1; off < 64; off <<= 1) {
                unsigned long long o = __shfl_xor(key, off);
                if (o > key) key = o;
            }
            if (lane == 0) sK[((it & 1) << 4) + wv] = key;
            __syncthreads();

            // cross-wave: 16 slots lane-parallel + 4-step shfl max
            unsigned long long gk = sK[((it & 1) << 4) + (lane & 15)];
#pragma unroll
            for (int off = 1; off < 16; off <<= 1) {
                unsigned long long o = __shfl_xor(gk, off);
                if (o > gk) gk = o;
            }
            const int widx = __builtin_amdgcn_readfirstlane(
                (int)(0xFFFFFFFFu - (unsigned)gk));
            // scalar fetch of winner coords (uniform address, cache-hot)
            cx = xb[widx]; cy = xb[NN + widx]; cz = xb[2 * NN + widx];
        }
    } else if (blk < 1028) {
        // ---------------- transpose points -> bf16 rows --------------------
        const int tb = blk - 4;
        const int b  = tb >> 8;
        const int n0 = (tb & 255) << 6;       // 64 points per tile
        unsigned short* sT = (unsigned short*)smem;  // [64][264]
        const int tn = t & 63, tc = t >> 6;   // tc 0..15
        for (int cc = tc; cc < 256; cc += 16) {
            float v = pts[((size_t)(b * 256 + cc)) * NN + n0 + tn];
            sT[tn * 264 + cc] = f2bf(v);
        }
        __syncthreads();
        unsigned short* ptsT = (unsigned short*)(ws + OFF_PTS);
        const int r = t >> 4, part = t & 15;  // 16 shorts per thread
        size_t ob = (((size_t)b * NN) + n0 + r) * 256 + part * 16;
        bf16x8* dst = (bf16x8*)(ptsT + ob);
        const bf16x8* src = (const bf16x8*)(sT + r * 264 + part * 16);
        dst[0] = src[0];
        dst[1] = src[1];
    } else if (blk < 1092) {
        // ---------------- point squared norms ------------------------------
        const int qb = blk - 1028;
        const int b = qb >> 4;
        const int n = ((qb & 15) << 10) + t;
        const float* xb = xyz + (size_t)b * 3 * NN;
        float X = xb[n], Y = xb[NN + n], Z = xb[2 * NN + n];
        float q = __fadd_rn(__fadd_rn(__fmul_rn(X, X), __fmul_rn(Y, Y)), __fmul_rn(Z, Z));
        ((float*)(ws + OFF_Q))[b * NN + n] = q;
    } else if (blk == 1092) {
        // ---------------- pack w1 into MFMA-B fragment order ---------------
        unsigned short* w1p = (unsigned short*)(ws + OFF_W1P);
        for (int e = t; e < 32 * 9 * 64 * 8; e += 1024) {
            int j = e & 7, lane = (e >> 3) & 63, rest = e >> 9;
            int kt = rest % 9, nt = rest / 9;
            int kk = kt * 32 + 4 * (lane >> 4) + (j & 3) + 16 * (j >> 2);
            int o  = nt * 16 + (lane & 15);
            float v = 0.f;
            if (kk < CIN) {
                int c = (kk < 256) ? (kk + 3) : (kk - 256);
                v = w1[o * CIN + c];
            }
            w1p[e] = f2bf(v);
        }
    } else if (blk == 1093) {
        unsigned short* w2p = (unsigned short*)(ws + OFF_W2P);
        for (int e = t; e < 32 * 16 * 64 * 8; e += 1024) {
            int j = e & 7, lane = (e >> 3) & 63, rest = e >> 9;
            int kt = rest & 15, nt = rest >> 4;
            int kk = kt * 32 + 4 * (lane >> 4) + (j & 3) + 16 * (j >> 2);
            int o  = nt * 16 + (lane & 15);
            w2p[e] = f2bf(w2[o * 512 + kk]);
        }
    }
}

// ---------------------------------------------------------------------------
// Kernel 2: ball query — one wave per query, ordered first-64 selection
// ---------------------------------------------------------------------------
__global__ __launch_bounds__(256) void k_ball(const float* __restrict__ xyz,
                                              unsigned char* __restrict__ ws)
{
    const int s    = (blockIdx.x << 2) + (threadIdx.x >> 6);  // 0..4095
    const int lane = threadIdx.x & 63;
    const int b    = s >> 10;
    const float* Q  = (const float*)(ws + OFF_Q) + b * NN;
    const float cx = ((const float*)(ws + OFF_CX))[s];
    const float cy = ((const float*)(ws + OFF_CY))[s];
    const float cz = ((const float*)(ws + OFF_CZ))[s];
    const float qc = __fadd_rn(__fadd_rn(__fmul_rn(cx, cx), __fmul_rn(cy, cy)),
                               __fmul_rn(cz, cz));
    const float* xb = xyz + (size_t)b * 3 * NN;
    int* gi = (int*)(ws + OFF_BIDX) + s * 64;

    int collected = 0;
    int first = -1;
    for (int c = 0; c < 256; c++) {
        const int n = (c << 6) + lane;
        float px = xb[n], py = xb[NN + n], pz = xb[2 * NN + n], qj = Q[n];
        float dot = __fadd_rn(__fadd_rn(__fmul_rn(cx, px), __fmul_rn(cy, py)),
                              __fmul_rn(cz, pz));
        float r = __fsub_rn(__fadd_rn(qc, qj), __fmul_rn(2.0f, dot));
        bool valid = !(r > R2C);
        unsigned long long m = __ballot(valid);
        if (m) {
            if (first < 0) first = (c << 6) + __builtin_ctzll(m);
            int rank = __popcll(m & ((1ull << lane) - 1ull));
            int slot = collected + rank;
            if (valid && slot < 64) gi[slot] = n;
            collected += __popcll(m);
            if (collected >= 64) break;
        }
    }
    if (collected < 64) {
        for (int k = collected + lane; k < 64; k += 64) gi[k] = first;
    }
}

// ---------------------------------------------------------------------------
// Kernel 3: gather + MLP(259->512->512, swish) + mean over 64 samples
// one block per (b, s); 8 waves; bf16 MFMA 16x16x32
// ---------------------------------------------------------------------------
__global__ __launch_bounds__(512) void k_mlp(const float* __restrict__ xyz,
                                             const float* __restrict__ b1,
                                             const float* __restrict__ b2,
                                             const unsigned char* __restrict__ ws,
                                             float* __restrict__ out)
{
    __shared__ __align__(16) unsigned short sFeat[64 * 296];  // 37,888 B
    __shared__ __align__(16) unsigned short sH1[64 * 520];    // 66,560 B
    __shared__ int sIdx[64];

    const int sblk = blockIdx.x;          // 0..4095
    const int b = sblk >> 10, sq = sblk & 1023;
    const int t = threadIdx.x;

    const int* gi = (const int*)(ws + OFF_BIDX) + sblk * 64;
    if (t < 64) sIdx[t] = gi[t];
    __syncthreads();

    // gather point features (cols 0..255)
    {
        const unsigned short* ptsT = (const unsigned short*)(ws + OFF_PTS);
        const int k = t >> 3, part = t & 7;
        const int n = sIdx[k];
        const bf16x8* src = (const bf16x8*)(ptsT + (((size_t)b * NN + n) * 256 + part * 32));
        bf16x8* dst = (bf16x8*)(sFeat + k * 296 + part * 32);
#pragma unroll
        for (int j = 0; j < 4; j++) dst[j] = src[j];
    }
    // grouped_norm (cols 256..258) + zero pad (259..287)
    if (t < 64) {
        const int n = sIdx[t];
        const float* xb = xyz + (size_t)b * 3 * NN;
        const float cx = ((const float*)(ws + OFF_CX))[sblk];
        const float cy = ((const float*)(ws + OFF_CY))[sblk];
        const float cz = ((const float*)(ws + OFF_CZ))[sblk];
        sFeat[t * 296 + 256] = f2bf(__fsub_rn(xb[n], cx));
        sFeat[t * 296 + 257] = f2bf(__fsub_rn(xb[NN + n], cy));
        sFeat[t * 296 + 258] = f2bf(__fsub_rn(xb[2 * NN + n], cz));
#pragma unroll
        for (int c = 259; c < 288; c++) sFeat[t * 296 + c] = 0;
    }
    __syncthreads();

    const int wv = t >> 6, lane = t & 63;
    const int l15 = lane & 15, g = lane >> 4;

    f32x4 acc[4][4];
#pragma unroll
    for (int i = 0; i < 4; i++)
#pragma unroll
        for (int j = 0; j < 4; j++) acc[i][j] = (f32x4){0.f, 0.f, 0.f, 0.f};

    // ---- layer 1: K = 288 (9 ktiles) ----
    const bf16x8* w1v = (const bf16x8*)(ws + OFF_W1P);
    for (int kt = 0; kt < 9; kt++) {
        bf16x8 af[4];
#pragma unroll
        for (int mt = 0; mt < 4; mt++) {
            const unsigned short* p = sFeat + (mt * 16 + l15) * 296 + kt * 32 + 4 * g;
            bf16x4 lo = *(const bf16x4*)p;
            bf16x4 hi = *(const bf16x4*)(p + 16);
            af[mt] = __builtin_shufflevector(lo, hi, 0, 1, 2, 3, 4, 5, 6, 7);
        }
        bf16x8 bfr[4];
#pragma unroll
        for (int nti = 0; nti < 4; nti++)
            bfr[nti] = w1v[((wv * 4 + nti) * 9 + kt) * 64 + lane];
#pragma unroll
        for (int mt = 0; mt < 4; mt++)
#pragma unroll
            for (int nti = 0; nti < 4; nti++)
                acc[mt][nti] = __builtin_amdgcn_mfma_f32_16x16x32_bf16(
                    af[mt], bfr[nti], acc[mt][nti], 0, 0, 0);
    }
    // epilogue 1: bias + swish -> sH1 (bf16)
#pragma unroll
    for (int mt = 0; mt < 4; mt++)
#pragma unroll
        for (int nti = 0; nti < 4; nti++) {
            const int o = (wv * 4 + nti) * 16 + l15;
            const float bias = b1[o];
#pragma unroll
            for (int r = 0; r < 4; r++) {
                float v = acc[mt][nti][r] + bias;
                float sw = v / (1.f + __expf(-v));
                sH1[(mt * 16 + g * 4 + r) * 520 + o] = f2bf(sw);
            }
        }
    __syncthreads();

    // ---- layer 2: K = 512 (16 ktiles) ----
#pragma unroll
    for (int i = 0; i < 4; i++)
#pragma unroll
        for (int j = 0; j < 4; j++) acc[i][j] = (f32x4){0.f, 0.f, 0.f, 0.f};

    const bf16x8* w2v = (const bf16x8*)(ws + OFF_W2P);
    for (int kt = 0; kt < 16; kt++) {
        bf16x8 af[4];
#pragma unroll
        for (int mt = 0; mt < 4; mt++) {
            const unsigned short* p = sH1 + (mt * 16 + l15) * 520 + kt * 32 + 4 * g;
            bf16x4 lo = *(const bf16x4*)p;
            bf16x4 hi = *(const bf16x4*)(p + 16);
            af[mt] = __builtin_shufflevector(lo, hi, 0, 1, 2, 3, 4, 5, 6, 7);
        }
        bf16x8 bfr[4];
#pragma unroll
        for (int nti = 0; nti < 4; nti++)
            bfr[nti] = w2v[((wv * 4 + nti) * 16 + kt) * 64 + lane];
#pragma unroll
        for (int mt = 0; mt < 4; mt++)
#pragma unroll
            for (int nti = 0; nti < 4; nti++)
                acc[mt][nti] = __builtin_amdgcn_mfma_f32_16x16x32_bf16(
                    af[mt], bfr[nti], acc[mt][nti], 0, 0, 0);
    }
    // epilogue 2: bias + swish + mean over the 64 samples
#pragma unroll
    for (int nti = 0; nti < 4; nti++) {
        float tot = 0.f;
        const int o = (wv * 4 + nti) * 16 + l15;
        const float bias = b2[o];
#pragma unroll
        for (int mt = 0; mt < 4; mt++) {
#pragma unroll
            for (int r = 0; r < 4; r++) {
                float v = acc[mt][nti][r] + bias;
                tot += v / (1.f + __expf(-v));
            }
        }
        tot += __shfl_xor(tot, 16);
        tot += __shfl_xor(tot, 32);
        if (lane < 16) {
            const int oo = (wv * 4 + nti) * 16 + lane;
            out[((size_t)b * 512 + oo) * 1024 + sq] = tot * 0.015625f;
        }
    }
}

extern "C" void kernel_launch(void* const* d_in, const int* in_sizes, int n_in,
                              void* d_out, int out_size, void* d_ws, size_t ws_size,
                              hipStream_t stream)
{
    const float* xyz = (const float*)d_in[0];
    const float* pts = (const float*)d_in[1];
    const float* w1  = (const float*)d_in[2];
    const float* b1  = (const float*)d_in[3];
    const float* w2  = (const float*)d_in[4];
    const float* b2  = (const float*)d_in[5];
    float* out = (float*)d_out;
    unsigned char* ws = (unsigned char*)d_ws;

    k_prep<<<1094, 1024, 0, stream>>>(xyz, pts, w1, w2, ws);
    k_ball<<<1024, 256, 0, stream>>>(xyz, ws);
    k_mlp<<<4096, 512, 0, stream>>>(xyz, b1, b2, ws, out);
}

// Round 8
// 1645.712 us; speedup vs baseline: 1.4725x; 1.4725x over previous
//
#include <hip/hip_runtime.h>
#include <hip/hip_bf16.h>
#include <stdint.h>

#define BB 4
#define NN 16384
#define SS 1024
#define KSAMP 64
#define DD 256
#define CIN 259
#define HH 512
#define R2C 0.04f

// workspace offsets (bytes, all 256-aligned)
#define OFF_PTS  0ull            // bf16 pointsT [B][N][256]  33,554,432
#define OFF_Q    33554432ull     // f32 point norms [B][N]       262,144
#define OFF_W1P  33816576ull     // bf16 packed w1               294,912
#define OFF_W2P  34111488ull     // bf16 packed w2               524,288
#define OFF_CX   34635776ull     // f32 centers x [4096]
#define OFF_CY   34652160ull
#define OFF_CZ   34668544ull
#define OFF_PROG 34684928ull     // int prog[4]

typedef __attribute__((ext_vector_type(8))) short bf16x8;
typedef __attribute__((ext_vector_type(4))) short bf16x4;
typedef __attribute__((ext_vector_type(4))) float f32x4;

__device__ __forceinline__ unsigned short f2bf(float f) {
    unsigned u = __float_as_uint(f);
    u = u + 0x7fffu + ((u >> 16) & 1u);   // round-to-nearest-even
    return (unsigned short)(u >> 16);
}

// ---------------------------------------------------------------------------
// Kernel A: points transpose->bf16 (blocks 0..1023) + point norms
//           (1024..1087) + weight packing (1088,1089). Runs first, ~40 us.
// ---------------------------------------------------------------------------
__global__ __launch_bounds__(1024) void k_prep2(const float* __restrict__ xyz,
                                                const float* __restrict__ pts,
                                                const float* __restrict__ w1,
                                                const float* __restrict__ w2,
                                                unsigned char* __restrict__ ws)
{
    __shared__ __align__(16) unsigned char smem[64 * 264 * 2];
    const int blk = blockIdx.x;
    const int t   = threadIdx.x;

    if (blk < 1024) {
        // ---------------- transpose points -> bf16 rows --------------------
        const int b  = blk >> 8;
        const int n0 = (blk & 255) << 6;      // 64 points per tile
        unsigned short* sT = (unsigned short*)smem;  // [64][264]
        const int tn = t & 63, tc = t >> 6;   // tc 0..15
        for (int cc = tc; cc < 256; cc += 16) {
            float v = pts[((size_t)(b * 256 + cc)) * NN + n0 + tn];
            sT[tn * 264 + cc] = f2bf(v);
        }
        __syncthreads();
        unsigned short* ptsT = (unsigned short*)(ws + OFF_PTS);
        const int r = t >> 4, part = t & 15;  // 16 shorts per thread
        size_t ob = (((size_t)b * NN) + n0 + r) * 256 + part * 16;
        bf16x8* dst = (bf16x8*)(ptsT + ob);
        const bf16x8* src = (const bf16x8*)(sT + r * 264 + part * 16);
        dst[0] = src[0];
        dst[1] = src[1];
    } else if (blk < 1088) {
        // ---------------- point squared norms ------------------------------
        const int qb = blk - 1024;
        const int b = qb >> 4;
        const int n = ((qb & 15) << 10) + t;
        const float* xb = xyz + (size_t)b * 3 * NN;
        float X = xb[n], Y = xb[NN + n], Z = xb[2 * NN + n];
        float q = __fadd_rn(__fadd_rn(__fmul_rn(X, X), __fmul_rn(Y, Y)), __fmul_rn(Z, Z));
        ((float*)(ws + OFF_Q))[b * NN + n] = q;
    } else if (blk == 1088) {
        // ---------------- pack w1 into MFMA-B fragment order ---------------
        unsigned short* w1p = (unsigned short*)(ws + OFF_W1P);
        for (int e = t; e < 32 * 9 * 64 * 8; e += 1024) {
            int j = e & 7, lane = (e >> 3) & 63, rest = e >> 9;
            int kt = rest % 9, nt = rest / 9;
            int kk = kt * 32 + 4 * (lane >> 4) + (j & 3) + 16 * (j >> 2);
            int o  = nt * 16 + (lane & 15);
            float v = 0.f;
            if (kk < CIN) {
                int c = (kk < 256) ? (kk + 3) : (kk - 256);
                v = w1[o * CIN + c];
            }
            w1p[e] = f2bf(v);
        }
    } else {
        unsigned short* w2p = (unsigned short*)(ws + OFF_W2P);
        for (int e = t; e < 32 * 16 * 64 * 8; e += 1024) {
            int j = e & 7, lane = (e >> 3) & 63, rest = e >> 9;
            int kt = rest & 15, nt = rest >> 4;
            int kk = kt * 32 + 4 * (lane >> 4) + (j & 3) + 16 * (j >> 2);
            int o  = nt * 16 + (lane & 15);
            w2p[e] = f2bf(w2[o * 512 + kk]);
        }
    }
}

// ---------------------------------------------------------------------------
// Kernel B: blocks 0..3 = FPS producers (round-1 verbatim FPS + agent-scope
//           atomic center publication). blocks 4..4099 = per-(b,s) consumers.
// LDS map (consumer): sFeat [0,37888) | sH1 [37888,104448) | sIdx [104448,104704)
// ---------------------------------------------------------------------------
__global__ __launch_bounds__(1024) void k_fused(const float* __restrict__ xyz,
                                                const float* __restrict__ b1,
                                                const float* __restrict__ b2,
                                                unsigned char* __restrict__ ws,
                                                float* __restrict__ out)
{
    __shared__ __align__(16) unsigned char smem[104832];
    const int blk = blockIdx.x;
    const int t   = threadIdx.x;
    int* prog = (int*)(ws + OFF_PROG);
    float* cxs = (float*)(ws + OFF_CX);
    float* cys = (float*)(ws + OFF_CY);
    float* czs = (float*)(ws + OFF_CZ);

    if (blk < 4) {
        // ================= FPS producer, batch b = blk (round-1 code) ======
        const int b = blk;
        const float* xb = xyz + (size_t)b * 3 * NN;
        float x[16], y[16], z[16], d[16];
        const int base = t * 16;
        const float4* xv = (const float4*)(xb + base);
        const float4* yv = (const float4*)(xb + NN + base);
        const float4* zv = (const float4*)(xb + 2 * NN + base);
#pragma unroll
        for (int i = 0; i < 4; i++) {
            float4 a = xv[i]; x[4*i]=a.x; x[4*i+1]=a.y; x[4*i+2]=a.z; x[4*i+3]=a.w;
            float4 c = yv[i]; y[4*i]=c.x; y[4*i+1]=c.y; y[4*i+2]=c.z; y[4*i+3]=c.w;
            float4 e = zv[i]; z[4*i]=e.x; z[4*i+1]=e.y; z[4*i+2]=e.z; z[4*i+3]=e.w;
        }
#pragma unroll
        for (int i = 0; i < 16; i++) d[i] = 1e10f;

        float* sC    = (float*)smem;         // [3] centroid
        float* sWMax = (float*)smem + 4;     // [16]
        int*   sWin  = (int*)((float*)smem + 20);

        // initial farthest = b (b < 16 -> owner thread 0)
        if (t == (b >> 4)) {
#pragma unroll
            for (int k = 0; k < 16; k++)
                if ((b & 15) == k) { sC[0] = x[k]; sC[1] = y[k]; sC[2] = z[k]; }
        }
        __syncthreads();

        for (int it = 0; it < SS; ++it) {
            const float cx = sC[0], cy = sC[1], cz = sC[2];
            if (t == 0) {
                // publish center via agent-scope atomics (coherence point,
                // visible to all XCDs)
                __hip_atomic_store(&cxs[(b << 10) + it], cx, __ATOMIC_RELAXED,
                                   __HIP_MEMORY_SCOPE_AGENT);
                __hip_atomic_store(&cys[(b << 10) + it], cy, __ATOMIC_RELAXED,
                                   __HIP_MEMORY_SCOPE_AGENT);
                __hip_atomic_store(&czs[(b << 10) + it], cz, __ATOMIC_RELAXED,
                                   __HIP_MEMORY_SCOPE_AGENT);
                // release every 8th iter: orders all prior center stores
                if ((it & 7) == 0)
                    __hip_atomic_store(&prog[b], it, __ATOMIC_RELEASE,
                                       __HIP_MEMORY_SCOPE_AGENT);
                *sWin = 0x7fffffff;
            }
            if (it == SS - 1) break;

            float bl = -1.0f;
#pragma unroll
            for (int k = 0; k < 16; k++) {
                float dx = __fsub_rn(x[k], cx);
                float dy = __fsub_rn(y[k], cy);
                float dz = __fsub_rn(z[k], cz);
                float s  = __fadd_rn(__fadd_rn(__fmul_rn(dx, dx), __fmul_rn(dy, dy)),
                                     __fmul_rn(dz, dz));
                float nd = fminf(d[k], s);
                d[k] = nd;
                bl = fmaxf(bl, nd);
            }
            float bm = bl;
#pragma unroll
            for (int off = 32; off; off >>= 1) bm = fmaxf(bm, __shfl_xor(bm, off));
            if ((t & 63) == 0) sWMax[t >> 6] = bm;
            __syncthreads();

            float gm = sWMax[0];
#pragma unroll
            for (int wv = 1; wv < 16; wv++) gm = fmaxf(gm, sWMax[wv]);

            if (bl == gm) {
                int cand = 0x7fffffff;
#pragma unroll
                for (int k = 15; k >= 0; k--) if (d[k] == gm) cand = base + k;
                atomicMin(sWin, cand);
            }
            __syncthreads();
            const int w = *sWin;
            if (t == (w >> 4)) {
                const int wk = w & 15;
#pragma unroll
                for (int k = 0; k < 16; k++)
                    if (wk == k) { sC[0] = x[k]; sC[1] = y[k]; sC[2] = z[k]; }
            }
            __syncthreads();
        }
        // final: all centers written -> release everything
        if (t == 0)
            __hip_atomic_store(&prog[b], SS, __ATOMIC_RELEASE,
                               __HIP_MEMORY_SCOPE_AGENT);
        return;
    }

    // ==================== consumer block: (b, s) ===========================
    const int i = blk - 4;
    const int b = i & 3, s = i >> 2;
    const int cs = (b << 10) + s;

    unsigned short* sFeat = (unsigned short*)smem;            // [64][296] = 37,888 B
    unsigned short* sH1   = (unsigned short*)(smem + 37888);  // [64][520] = 66,560 B
    int*            sIdx  = (int*)(smem + 104448);            // [64]      =    256 B

    // ---- phase 0: wait until center s is published (prog init = -1) ----
    if (t == 0) {
        while (__hip_atomic_load(&prog[b], __ATOMIC_ACQUIRE,
                                 __HIP_MEMORY_SCOPE_AGENT) <= s)
            __builtin_amdgcn_s_sleep(8);
    }
    __syncthreads();

    // read center via agent atomics (coherence point; ordered by release)
    const float cx = __hip_atomic_load(&cxs[cs], __ATOMIC_RELAXED,
                                       __HIP_MEMORY_SCOPE_AGENT);
    const float cy = __hip_atomic_load(&cys[cs], __ATOMIC_RELAXED,
                                       __HIP_MEMORY_SCOPE_AGENT);
    const float cz = __hip_atomic_load(&czs[cs], __ATOMIC_RELAXED,
                                       __HIP_MEMORY_SCOPE_AGENT);
    const float* xb = xyz + (size_t)b * 3 * NN;

    // ---- phase 1: ball query (wave 0 only) -> sIdx ----
    if (t < 64) {
        const int lane = t;
        const float* Q = (const float*)(ws + OFF_Q) + b * NN;
        const float qc = __fadd_rn(__fadd_rn(__fmul_rn(cx, cx), __fmul_rn(cy, cy)),
                                   __fmul_rn(cz, cz));
        int collected = 0;
        int first = -1;
        for (int c = 0; c < 256; c++) {
            const int n = (c << 6) + lane;
            float px = xb[n], py = xb[NN + n], pz = xb[2 * NN + n], qj = Q[n];
            float dot = __fadd_rn(__fadd_rn(__fmul_rn(cx, px), __fmul_rn(cy, py)),
                                  __fmul_rn(cz, pz));
            float r = __fsub_rn(__fadd_rn(qc, qj), __fmul_rn(2.0f, dot));
            bool valid = !(r > R2C);
            unsigned long long m = __ballot(valid);
            if (m) {
                if (first < 0) first = (c << 6) + __builtin_ctzll(m);
                int rank = __popcll(m & ((1ull << lane) - 1ull));
                int slot = collected + rank;
                if (valid && slot < 64) sIdx[slot] = n;
                collected += __popcll(m);
                if (collected >= 64) break;
            }
        }
        if (collected < 64) {
            for (int k = collected + lane; k < 64; k += 64) sIdx[k] = first;
        }
    }
    __syncthreads();

    // ---- phase 2: gather features (FULL 256 shorts per point) ----
    {
        const unsigned short* ptsT = (const unsigned short*)(ws + OFF_PTS);
        const int k = t >> 4, part = t & 15;   // 64 pts x 16 parts x 16 shorts
        const int n = sIdx[k];
        const bf16x8* src = (const bf16x8*)(ptsT + ((size_t)b * NN + n) * 256 + part * 16);
        bf16x8* dst = (bf16x8*)(sFeat + k * 296 + part * 16);
        dst[0] = src[0];
        dst[1] = src[1];
    }
    if (t < 64) {
        const int n = sIdx[t];
        sFeat[t * 296 + 256] = f2bf(__fsub_rn(xb[n], cx));
        sFeat[t * 296 + 257] = f2bf(__fsub_rn(xb[NN + n], cy));
        sFeat[t * 296 + 258] = f2bf(__fsub_rn(xb[2 * NN + n], cz));
#pragma unroll
        for (int c = 259; c < 288; c++) sFeat[t * 296 + c] = 0;
    }
    __syncthreads();

    const int wv = t >> 6, lane = t & 63;
    const int l15 = lane & 15, g = lane >> 4;

    f32x4 acc[4][2];
#pragma unroll
    for (int a = 0; a < 4; a++)
#pragma unroll
        for (int j = 0; j < 2; j++) acc[a][j] = (f32x4){0.f, 0.f, 0.f, 0.f};

    // ---- layer 1: K = 288 (9 ktiles); 16 waves x 2 ntiles ----
    const bf16x8* w1v = (const bf16x8*)(ws + OFF_W1P);
    for (int kt = 0; kt < 9; kt++) {
        bf16x8 af[4];
#pragma unroll
        for (int mt = 0; mt < 4; mt++) {
            const unsigned short* p = sFeat + (mt * 16 + l15) * 296 + kt * 32 + 4 * g;
            bf16x4 lo = *(const bf16x4*)p;
            bf16x4 hi = *(const bf16x4*)(p + 16);
            af[mt] = __builtin_shufflevector(lo, hi, 0, 1, 2, 3, 4, 5, 6, 7);
        }
        bf16x8 bfr[2];
#pragma unroll
        for (int nti = 0; nti < 2; nti++)
            bfr[nti] = w1v[((wv * 2 + nti) * 9 + kt) * 64 + lane];
#pragma unroll
        for (int mt = 0; mt < 4; mt++)
#pragma unroll
            for (int nti = 0; nti < 2; nti++)
                acc[mt][nti] = __builtin_amdgcn_mfma_f32_16x16x32_bf16(
                    af[mt], bfr[nti], acc[mt][nti], 0, 0, 0);
    }
    // epilogue 1: bias + swish -> sH1 (bf16)
#pragma unroll
    for (int mt = 0; mt < 4; mt++)
#pragma unroll
        for (int nti = 0; nti < 2; nti++) {
            const int o = (wv * 2 + nti) * 16 + l15;
            const float bias = b1[o];
#pragma unroll
            for (int r = 0; r < 4; r++) {
                float v = acc[mt][nti][r] + bias;
                float sw = v / (1.f + __expf(-v));
                sH1[(mt * 16 + g * 4 + r) * 520 + o] = f2bf(sw);
            }
        }
    __syncthreads();

    // ---- layer 2: K = 512 (16 ktiles) ----
#pragma unroll
    for (int a = 0; a < 4; a++)
#pragma unroll
        for (int j = 0; j < 2; j++) acc[a][j] = (f32x4){0.f, 0.f, 0.f, 0.f};

    const bf16x8* w2v = (const bf16x8*)(ws + OFF_W2P);
    for (int kt = 0; kt < 16; kt++) {
        bf16x8 af[4];
#pragma unroll
        for (int mt = 0; mt < 4; mt++) {
            const unsigned short* p = sH1 + (mt * 16 + l15) * 520 + kt * 32 + 4 * g;
            bf16x4 lo = *(const bf16x4*)p;
            bf16x4 hi = *(const bf16x4*)(p + 16);
            af[mt] = __builtin_shufflevector(lo, hi, 0, 1, 2, 3, 4, 5, 6, 7);
        }
        bf16x8 bfr[2];
#pragma unroll
        for (int nti = 0; nti < 2; nti++)
            bfr[nti] = w2v[((wv * 2 + nti) * 16 + kt) * 64 + lane];
#pragma unroll
        for (int mt = 0; mt < 4; mt++)
#pragma unroll
            for (int nti = 0; nti < 2; nti++)
                acc[mt][nti] = __builtin_amdgcn_mfma_f32_16x16x32_bf16(
                    af[mt], bfr[nti], acc[mt][nti], 0, 0, 0);
    }
    // epilogue 2: bias + swish + mean over the 64 samples
#pragma unroll
    for (int nti = 0; nti < 2; nti++) {
        float tot = 0.f;
        const int o = (wv * 2 + nti) * 16 + l15;
        const float bias = b2[o];
#pragma unroll
        for (int mt = 0; mt < 4; mt++) {
#pragma unroll
            for (int r = 0; r < 4; r++) {
                float v = acc[mt][nti][r] + bias;
                tot += v / (1.f + __expf(-v));
            }
        }
        tot += __shfl_xor(tot, 16);
        tot += __shfl_xor(tot, 32);
        if (lane < 16) {
            const int oo = (wv * 2 + nti) * 16 + lane;
            out[((size_t)b * 512 + oo) * 1024 + s] = tot * 0.015625f;
        }
    }
}

extern "C" void kernel_launch(void* const* d_in, const int* in_sizes, int n_in,
                              void* d_out, int out_size, void* d_ws, size_t ws_size,
                              hipStream_t stream)
{
    const float* xyz = (const float*)d_in[0];
    const float* pts = (const float*)d_in[1];
    const float* w1  = (const float*)d_in[2];
    const float* b1  = (const float*)d_in[3];
    const float* w2  = (const float*)d_in[4];
    const float* b2  = (const float*)d_in[5];
    float* out = (float*)d_out;
    unsigned char* ws = (unsigned char*)d_ws;

    // progress counters must start negative (blocks all consumers) each call
    hipMemsetAsync((void*)(ws + OFF_PROG), 0xFF, 16, stream);
    k_prep2<<<1090, 1024, 0, stream>>>(xyz, pts, w1, w2, ws);
    k_fused<<<4100, 1024, 0, stream>>>(xyz, b1, b2, ws, out);
}